// Round 8
// baseline (93.933 us; speedup 1.0000x reference)
//
#include <hip/hip_runtime.h>
#include <hip/hip_bf16.h>
#include <stdint.h>

#define E_EXP 16
#define H_DIM 1024
#define B_TOK 4096
#define GBN 64         // B panel rows per block; [64][1024] bf16 = 128 KB LDS
#define NSLOT 16       // one slot per nb
#define KS 16          // router k-splits
#define KC 64          // H_DIM / KS
#define RTM 128        // router token tile
#define RSTRIDE (KC + 4)

typedef short bf16x8 __attribute__((ext_vector_type(8)));
typedef float f32x4 __attribute__((ext_vector_type(4)));

__device__ __forceinline__ unsigned short f2bf(float x) {
  union { float f; unsigned u; } v; v.f = x;
  unsigned r = v.u + 0x7FFFu + ((v.u >> 16) & 1u);   // RNE
  return (unsigned short)(r >> 16);
}

__device__ __forceinline__ void gload_lds16(const void* g, void* l) {
  __builtin_amdgcn_global_load_lds(
      (const __attribute__((address_space(1))) void*)g,
      (__attribute__((address_space(3))) void*)l, 16, 0, 0);
}

// ---------------- Router GEMM: partial logits [KS][B][16] + emb->bf16 ------
__global__ __launch_bounds__(256) void k_router_gemm(
    const float* __restrict__ emb, const float* __restrict__ rw,
    unsigned short* __restrict__ emb_bf, float* __restrict__ part)
{
  __shared__ float embL[RTM * RSTRIDE];   // 128 rows x 64 k, stride 68 (2-way banks)
  __shared__ float rwL[KC * E_EXP];       // 64 x 16, broadcast reads

  const int t0 = blockIdx.x * RTM;
  const int ks = blockIdx.y;
  const int tid = threadIdx.x;

#pragma unroll
  for (int it = 0; it < 8; ++it) {
    const int i = tid + 256 * it;       // 0..2047 = 128 rows x 16 f32x4
    const int row = i >> 4;
    const int c4 = i & 15;
    const size_t goff = (size_t)(t0 + row) * H_DIM + ks * KC + c4 * 4;
    const f32x4 v = *(const f32x4*)(emb + goff);
    ushort4 o;
    o.x = f2bf(v[0]); o.y = f2bf(v[1]); o.z = f2bf(v[2]); o.w = f2bf(v[3]);
    *(ushort4*)(emb_bf + goff) = o;
    *(f32x4*)(embL + row * RSTRIDE + c4 * 4) = v;
  }
  {
    const f32x4 v = *(const f32x4*)(rw + (size_t)ks * (KC * E_EXP) + tid * 4);
    *(f32x4*)(rwL + tid * 4) = v;
  }
  __syncthreads();

  const int w = tid >> 6, lane = tid & 63;
  const int tg = lane & 15, eg = lane >> 4;
  const int ta = w * 32 + tg, tb = ta + 16;   // 2 tokens per lane, 4 experts each

  f32x4 accA = {0.f, 0.f, 0.f, 0.f};
  f32x4 accB = {0.f, 0.f, 0.f, 0.f};
#pragma unroll
  for (int k4 = 0; k4 < KC / 4; ++k4) {
    const f32x4 e0 = *(const f32x4*)(embL + ta * RSTRIDE + k4 * 4);
    const f32x4 e1 = *(const f32x4*)(embL + tb * RSTRIDE + k4 * 4);
#pragma unroll
    for (int h = 0; h < 4; ++h) {
      const f32x4 r = *(const f32x4*)(rwL + (k4 * 4 + h) * E_EXP + eg * 4);
      accA += e0[h] * r;
      accB += e1[h] * r;
    }
  }

  *(f32x4*)(part + ((size_t)ks * B_TOK + t0 + ta) * E_EXP + eg * 4) = accA;
  *(f32x4*)(part + ((size_t)ks * B_TOK + t0 + tb) * E_EXP + eg * 4) = accB;
}

// ---------------- Router select: reduce partials, top-2, compaction --------
__global__ __launch_bounds__(256) void k_router_select(
    const float* __restrict__ part, const float* __restrict__ rb,
    int* __restrict__ counts, int* __restrict__ lists,
    int4* __restrict__ meta, float2* __restrict__ wts)
{
  __shared__ int lcnt[E_EXP];
  __shared__ int base[E_EXP];
  const int tid = threadIdx.x;
  const int t = blockIdx.x * 256 + tid;
  if (tid < E_EXP) lcnt[tid] = 0;

  float lg[16];
#pragma unroll
  for (int q = 0; q < 4; ++q) {
    const f32x4 b = *(const f32x4*)(rb + q * 4);
    lg[q * 4 + 0] = b[0]; lg[q * 4 + 1] = b[1];
    lg[q * 4 + 2] = b[2]; lg[q * 4 + 3] = b[3];
  }
#pragma unroll
  for (int s = 0; s < KS; ++s) {
#pragma unroll
    for (int q = 0; q < 4; ++q) {
      const f32x4 v = *(const f32x4*)(part + ((size_t)s * B_TOK + t) * E_EXP + q * 4);
      lg[q * 4 + 0] += v[0]; lg[q * 4 + 1] += v[1];
      lg[q * 4 + 2] += v[2]; lg[q * 4 + 3] += v[3];
    }
  }

  float best = -1e30f; int b0 = 0;
#pragma unroll
  for (int e = 0; e < 16; ++e)
    if (lg[e] > best) { best = lg[e]; b0 = e; }
  float best2 = -1e30f; int b1i = 0;
#pragma unroll
  for (int e = 0; e < 16; ++e)
    if (e != b0 && lg[e] > best2) { best2 = lg[e]; b1i = e; }

  __syncthreads();                       // lcnt zeroed
  const int l0 = atomicAdd(&lcnt[b0], 1);
  const int l1 = atomicAdd(&lcnt[b1i], 1);
  __syncthreads();
  if (tid < E_EXP) base[tid] = atomicAdd(&counts[tid], lcnt[tid]);
  __syncthreads();

  const int p0 = base[b0] + l0;
  const int p1 = base[b1i] + l1;
  lists[b0 * B_TOK + p0] = t;
  lists[b1i * B_TOK + p1] = t;
  meta[t] = make_int4(b0, b1i, p0, p1);
  const float e1v = expf(best2 - best);
  const float w0 = 1.f / (1.f + e1v);
  wts[t] = make_float2(w0, e1v * w0);
}

// ---------------- W1 [e][h][d] fp32 -> W1T [e][d][h] bf16 ------------------
__global__ __launch_bounds__(256) void k_w1t(const float* __restrict__ w1,
                                             unsigned short* __restrict__ w1t)
{
  __shared__ unsigned short tile[64][65];
  const int e = blockIdx.z;
  const int ht = blockIdx.x, dt = blockIdx.y;
  const float* src = w1 + ((size_t)e * H_DIM + ht * 64) * H_DIM + dt * 64;
  const int tr = threadIdx.x >> 4;
  const int tc = threadIdx.x & 15;
#pragma unroll
  for (int i = 0; i < 4; ++i) {
    const int r = tr + i * 16;
    const float4 v = *(const float4*)(src + (size_t)r * H_DIM + tc * 4);
    tile[r][tc * 4 + 0] = f2bf(v.x);
    tile[r][tc * 4 + 1] = f2bf(v.y);
    tile[r][tc * 4 + 2] = f2bf(v.z);
    tile[r][tc * 4 + 3] = f2bf(v.w);
  }
  __syncthreads();
  unsigned short* dst = w1t + ((size_t)e * H_DIM + dt * 64) * H_DIM + ht * 64;
  const int wr = threadIdx.x >> 3;
  const int wc = threadIdx.x & 7;
#pragma unroll
  for (int i = 0; i < 2; ++i) {
    const int r = wr + i * 32;
    ushort4 t0, t1;
    t0.x = tile[wc * 8 + 0][r]; t0.y = tile[wc * 8 + 1][r];
    t0.z = tile[wc * 8 + 2][r]; t0.w = tile[wc * 8 + 3][r];
    t1.x = tile[wc * 8 + 4][r]; t1.y = tile[wc * 8 + 5][r];
    t1.z = tile[wc * 8 + 6][r]; t1.w = tile[wc * 8 + 7][r];
    *(ushort4*)(dst + (size_t)r * H_DIM + wc * 8) = t0;
    *(ushort4*)(dst + (size_t)r * H_DIM + wc * 8 + 4) = t1;
  }
}

// ---------------- Grouped GEMM, barrier-free K-loop ------------------------
// One block per (expert, nb): B panel [64][1024] bf16 staged ONCE into 128 KB
// LDS (XOR-swizzled, involution on source + read). Then zero __syncthreads:
// each wave owns 64 token rows, A-fragments gathered straight from global
// (L2-resident; per-lane 16B, k advances via imm offset), 16 MFMA per kk.
// XCD-grouped: bid&7 == e&7 -> expert's A rows (~1 MB) stay in one L2.
__global__ __launch_bounds__(512, 2) void k_moe_gemm(
    const unsigned short* __restrict__ emb_bf,
    const unsigned short* __restrict__ w1t,
    const float* __restrict__ b1, const float* __restrict__ w2,
    const int* __restrict__ counts, const int* __restrict__ lists,
    float* __restrict__ outbuf)
{
  const int bid = blockIdx.x;                 // 256 blocks
  const int e  = (bid & 7) + 8 * ((bid >> 3) & 1);
  const int nb = bid >> 4;                    // 0..15
  const int cnt = counts[e];

  __shared__ unsigned short lB[GBN * H_DIM];  // 128 KB

  const int tid = threadIdx.x;
  const int w = tid >> 6, lane = tid & 63;
  const int lr = lane & 15, lg = lane >> 4;

  const unsigned short* w1tb = w1t + ((size_t)e * H_DIM + nb * GBN) * H_DIM;

  // stage B once: 128 chunks of 1 KB, 16 per wave; linear dest + pre-swizzled src
#pragma unroll
  for (int i = 0; i < 16; ++i) {
    const int c = w * 16 + i;
    const int n = c >> 1, half = c & 1;
    const int sb = (half * 1024 + lane * 16) ^ ((n & 7) << 4);
    gload_lds16((const char*)w1tb + n * 2048 + sb, (char*)lB + c * 1024);
  }
  __syncthreads();   // drains vmcnt(0): panel resident; last barrier in kernel

  const float* b1e = b1 + (size_t)e * H_DIM + nb * GBN;
  const float* w2e = w2 + (size_t)e * H_DIM + nb * GBN;

  for (int base = w * 64; base < cnt; base += 512) {
    // per-lane A row pointers: lane holds row base+m*16+lr, k-elems lg*8..+7
    const unsigned short* aP[4];
#pragma unroll
    for (int m = 0; m < 4; ++m) {
      const int p = base + m * 16 + lr;
      const int tok = lists[e * B_TOK + (p < cnt ? p : 0)];
      aP[m] = emb_bf + (size_t)tok * H_DIM + lg * 8;
    }

    f32x4 acc[4][4];
#pragma unroll
    for (int m = 0; m < 4; ++m)
#pragma unroll
      for (int n = 0; n < 4; ++n) acc[m][n] = (f32x4){0.f, 0.f, 0.f, 0.f};

#pragma unroll 8
    for (int kk = 0; kk < 32; ++kk) {
      bf16x8 af[4], bfr[4];
#pragma unroll
      for (int m = 0; m < 4; ++m)
        af[m] = *(const bf16x8*)(aP[m] + kk * 32);
#pragma unroll
      for (int j = 0; j < 4; ++j) {
        const int col = j * 16 + lr;
        bfr[j] = *(const bf16x8*)((const char*)lB + col * 2048 +
                                  ((kk * 64 + lg * 16) ^ ((col & 7) << 4)));
      }
      __builtin_amdgcn_s_setprio(1);
#pragma unroll
      for (int m = 0; m < 4; ++m)
#pragma unroll
        for (int n = 0; n < 4; ++n)
          acc[m][n] = __builtin_amdgcn_mfma_f32_16x16x32_bf16(af[m], bfr[n], acc[m][n], 0, 0, 0);
      __builtin_amdgcn_s_setprio(0);
    }

    // epilogue: relu(acc + b1) * w2, reduce over this block's 64 cols
    float rs[4][4];
#pragma unroll
    for (int m = 0; m < 4; ++m)
#pragma unroll
      for (int r4 = 0; r4 < 4; ++r4) rs[m][r4] = 0.f;

#pragma unroll
    for (int j = 0; j < 4; ++j) {
      const int d = j * 16 + lr;
      const float bb = b1e[d];
      const float ww = w2e[d];
#pragma unroll
      for (int m = 0; m < 4; ++m)
#pragma unroll
        for (int r4 = 0; r4 < 4; ++r4) {
          float v = acc[m][j][r4] + bb;
          v = fmaxf(v, 0.f);
          rs[m][r4] = fmaf(v, ww, rs[m][r4]);
        }
    }
#pragma unroll
    for (int mask = 8; mask >= 1; mask >>= 1) {
#pragma unroll
      for (int m = 0; m < 4; ++m)
#pragma unroll
        for (int r4 = 0; r4 < 4; ++r4) rs[m][r4] += __shfl_xor(rs[m][r4], mask, 64);
    }

    if (lr == 0) {
      float* ob = outbuf + ((size_t)nb * E_EXP + e) * B_TOK + base;
#pragma unroll
      for (int m = 0; m < 4; ++m)
#pragma unroll
        for (int r4 = 0; r4 < 4; ++r4)
          ob[m * 16 + lg * 4 + r4] = rs[m][r4];
    }
  }
}

// ---------------- Combine: gather 2 experts x 16 partial slots -------------
__global__ __launch_bounds__(256) void k_combine(
    const int4* __restrict__ meta, const float2* __restrict__ wts,
    const float* __restrict__ outbuf, const float* __restrict__ b2,
    float* __restrict__ out)
{
  const int t = blockIdx.x * 256 + threadIdx.x;
  if (t >= B_TOK) return;
  const int4 m = meta[t];
  const float2 w = wts[t];
  float o0 = b2[m.x], o1 = b2[m.y];
#pragma unroll
  for (int s = 0; s < NSLOT; ++s) {
    o0 += outbuf[((size_t)s * E_EXP + m.x) * B_TOK + m.z];
    o1 += outbuf[((size_t)s * E_EXP + m.y) * B_TOK + m.w];
  }
  out[t] = w.x * o0 + w.y * o1;
}

extern "C" void kernel_launch(void* const* d_in, const int* in_sizes, int n_in,
                              void* d_out, int out_size, void* d_ws, size_t ws_size,
                              hipStream_t stream)
{
  const float* emb = (const float*)d_in[0];
  const float* rw  = (const float*)d_in[1];
  const float* rb  = (const float*)d_in[2];
  const float* w1  = (const float*)d_in[3];
  const float* b1  = (const float*)d_in[4];
  const float* w2  = (const float*)d_in[5];
  const float* b2  = (const float*)d_in[6];
  float* out = (float*)d_out;

  char* ws = (char*)d_ws;
  size_t cur = 0;
  auto alloc = [&](size_t bytes) -> void* {
    void* p = ws + cur;
    cur += (bytes + 255) & ~(size_t)255;
    return p;
  };
  int*            counts = (int*)alloc(64);
  int4*           meta   = (int4*)alloc((size_t)B_TOK * 16);
  float2*         wts    = (float2*)alloc((size_t)B_TOK * 8);
  int*            lists  = (int*)alloc((size_t)E_EXP * B_TOK * 4);
  float*          outbuf = (float*)alloc((size_t)NSLOT * E_EXP * B_TOK * 4);
  float*          part   = (float*)alloc((size_t)KS * B_TOK * E_EXP * 4);
  unsigned short* emb_bf = (unsigned short*)alloc((size_t)B_TOK * H_DIM * 2);
  unsigned short* w1t    = (unsigned short*)alloc((size_t)E_EXP * H_DIM * H_DIM * 2);

  hipMemsetAsync(counts, 0, 64, stream);
  k_router_gemm<<<dim3(B_TOK / RTM, KS), 256, 0, stream>>>(emb, rw, emb_bf, part);
  k_router_select<<<B_TOK / 256, 256, 0, stream>>>(part, rb, counts, lists, meta, wts);
  k_w1t<<<dim3(16, 16, 16), 256, 0, stream>>>(w1, w1t);
  k_moe_gemm<<<dim3(256), 512, 0, stream>>>(emb_bf, w1t, b1, w2, counts, lists, outbuf);
  k_combine<<<B_TOK / 256, 256, 0, stream>>>(meta, wts, outbuf, b2, out);
}